// Round 1
// baseline (285.044 us; speedup 1.0000x reference)
//
#include <hip/hip_runtime.h>
#include <hip/hip_bf16.h>
#include <stdint.h>

// ---------------------------------------------------------------------------
// CausalSelfAttention: x(4,2048,1024) fp32 -> out fp32
// qkv = x@w_attn+b_attn; flash-attn causal (H=16,hd=64); out = attn@w_proj+b_proj
// R7: GEMMs rewritten as gemm256 (BM=256,BN=128,BK=64, 8 waves 4x2, 64x64/wave):
//   - counted s_waitcnt vmcnt(4) at K-tile boundaries (never drains in-loop),
//     raw s_barrier (no compiler vmcnt(0) drain) -> loads span barriers (T3+T4)
//   - chunk-XOR LDS swizzle (chunk^=row&7) via pre-swizzled global source +
//     swizzled ds_read: conflict-free ds_read_b128 (T2)
//   - s_setprio(1) around each 16-MFMA cluster (T5)
//   - QKV: 768 blocks = 3/CU exact; proj: 256 blocks = 1/CU exact (no tail)
// attn (R6): paired Q-tiles, triple-buffered K/V ring, exp2 softmax (unchanged).
// Workspace: xb 16MB (aliased by Vt after QKV GEMM) | wat 6MB | wpt 2MB |
//            qkv 48MB | attn 16MB  = 88 MB
// ---------------------------------------------------------------------------

typedef uint16_t u16;
typedef __bf16 bf16x8 __attribute__((ext_vector_type(8)));
typedef __bf16 bf16x4 __attribute__((ext_vector_type(4)));
typedef short s16x4 __attribute__((ext_vector_type(4)));
typedef float f32x4 __attribute__((ext_vector_type(4)));

#define S_LEN 2048
#define DMODEL 1024
#define NHEAD 16
#define HDIM 64
#define MTOT 8192   // B*S
#define NQKV 3072

__device__ __forceinline__ u16 f2bf(float f) {
    union { float f; uint32_t u; } v; v.f = f;
    uint32_t u = v.u;
    return (u16)((u + 0x7fffu + ((u >> 16) & 1u)) >> 16);  // RNE
}

__device__ __forceinline__ s16x4 bits4(bf16x4 v) {
    union { bf16x4 b; s16x4 s; } u; u.b = v; return u.s;
}

// D = A*B + C, 16x16x16 bf16 (A,B: 4 bf16/lane, k = q4*4+j)
__device__ __forceinline__ f32x4 mfma16(bf16x4 a, bf16x4 b, f32x4 c) {
    return __builtin_amdgcn_mfma_f32_16x16x16bf16_1k(bits4(a), bits4(b), c, 0, 0, 0);
}

__device__ __forceinline__ void async_load16(const void* g, void* l) {
    __builtin_amdgcn_global_load_lds(
        (__attribute__((address_space(1))) void*)g,
        (__attribute__((address_space(3))) void*)l,
        16, 0, 0);
}

// ---- prep: fp32 -> bf16 (vectorized) --------------------------------------
__global__ void convert_x_kernel(const float4* __restrict__ in, ushort4* __restrict__ out, int n4) {
    int i = blockIdx.x * 256 + threadIdx.x;
    if (i < n4) {
        float4 f = in[i];
        ushort4 o;
        o.x = f2bf(f.x); o.y = f2bf(f.y); o.z = f2bf(f.z); o.w = f2bf(f.w);
        out[i] = o;
    }
}

// ---- prep: transpose + convert: in (R x C) fp32 -> out (C x R) bf16 --------
__global__ void transpose_bf16_kernel(const float* __restrict__ in, u16* __restrict__ out, int R, int C) {
    __shared__ float tile[64][65];
    int r0 = blockIdx.y * 64, c0 = blockIdx.x * 64;
    #pragma unroll
    for (int i = 0; i < 16; ++i) {
        int idx = threadIdx.x + i * 256;
        int r = idx >> 6, c = idx & 63;
        tile[r][c] = in[(size_t)(r0 + r) * C + c0 + c];
    }
    __syncthreads();
    #pragma unroll
    for (int i = 0; i < 16; ++i) {
        int idx = threadIdx.x + i * 256;
        int c = idx >> 6, r = idx & 63;
        out[(size_t)(c0 + c) * R + r0 + r] = f2bf(tile[r][c]);
    }
}

// ---- V transpose: qkv V-section (token-major) -> Vt[bh][d][s] --------------
__global__ void transpose_v_kernel(const u16* __restrict__ qkv, u16* __restrict__ vt) {
    __shared__ u16 tile[64 * 66];
    const int tid = threadIdx.x;
    const int stile = blockIdx.x, bh = blockIdx.y;
    const int b = bh >> 4, h = bh & 15;
    const u16* src = qkv + ((size_t)b * S_LEN + stile * 64) * NQKV + 2 * DMODEL + h * HDIM;
    #pragma unroll
    for (int it = 0; it < 2; ++it) {
        int item = it * 256 + tid;
        int s = item >> 3, d0 = (item & 7) * 8;
        bf16x8 v = *(const bf16x8*)(src + (size_t)s * NQKV + d0);
        const u16* vu = (const u16*)&v;
        #pragma unroll
        for (int j = 0; j < 8; ++j) tile[(d0 + j) * 66 + s] = vu[j];
    }
    __syncthreads();
    #pragma unroll
    for (int it = 0; it < 2; ++it) {
        int item = it * 256 + tid;
        int d = item >> 3, s0 = (item & 7) * 8;
        union { u16 u[8]; uint4 v; } pk;
        #pragma unroll
        for (int j = 0; j < 8; ++j) pk.u[j] = tile[d * 66 + s0 + j];
        *(uint4*)(vt + ((size_t)bh * 64 + d) * S_LEN + stile * 64 + s0) = pk.v;
    }
}

// ---- GEMM256: C[M,N] = A[M,K] @ Bt[N,K]^T + bias ---------------------------
// BM=256, BN=128, BK=64; 512 threads = 8 waves (wm=wave&3 along M, wn=wave>>2
// along N), per-wave 64x64 output (mf 0..3, nf 0..3, 16x16x32 MFMA).
// LDS ring (96 KiB): A = 4 half-slots [parity][half] of 128x64 bf16 (16KB),
// B = 2 slots of 128x64. Element (r,k): chunk (k>>3) stored at slot
// chunk^(r&7)  -> ds_read_b128 conflict-free; staging writes LINEAR LDS
// (global_load_lds) from inverse-swizzled global source (both-sides rule).
// Per K-tile: phase A computes mf{0,1} from A-half0 (B-frags read once, held
// in regs), phase B computes mf{2,3} from A-half1. Each half-slot is read in
// exactly one phase -> freed mid-tile for the prefetch ring:
//   phase A stages A.h1(t+1); phase B stages A.h0(t+2)+B(t+2);
//   boundary wait = s_waitcnt vmcnt(4) (the 4 phase-B loads stay in flight).
// Requires M%256==0, N%128==0, K%64==0, grid%8==0, M/256 power of two.
template<bool OUT_BF16>
__global__ __launch_bounds__(512, 2) void gemm256(
    const u16* __restrict__ A, const u16* __restrict__ Bt,
    const float* __restrict__ bias, void* __restrict__ C,
    int M, int N, int K)
{
    __shared__ __attribute__((aligned(16))) u16 sm[49152];   // 96 KiB
    const int tid = threadIdx.x;
    const int wave = tid >> 6, lane = tid & 63;
    const int l15 = lane & 15, q4 = lane >> 4;
    const int wm = wave & 3, wn = wave >> 2;

    // bijective XCD swizzle (grid % 8 == 0), then mb-major within nb-columns
    const int nwg = (int)gridDim.x;
    const int bid = (int)blockIdx.x;
    const int wg = (bid & 7) * (nwg >> 3) + (bid >> 3);
    const int MB = M >> 8;                 // power of two (32 here)
    const int mb = wg & (MB - 1);
    const int nb = wg / MB;
    const int m0 = mb << 8, n0 = nb << 7;

    const u16* Ag = A + (size_t)m0 * K;
    const u16* Bg = Bt + (size_t)n0 * K;

    // staging: per thread 2x16B per half-tile; linear LDS dest, swizzled src
    const int srow = tid >> 3;
    const size_t goff0 = (size_t)srow * K + (size_t)(((tid & 7) ^ (srow & 7)) * 8);
    const size_t goff1 = goff0 + (size_t)64 * K;
    const int ldso = tid * 8;

    // ds_read offsets (u16 units); r&7 == l15&7 for all frag rows
    const int ck0 = (q4 ^ (l15 & 7)) * 8;
    const int ck1 = ((4 + q4) ^ (l15 & 7)) * 8;
    const int ra0 = (wm * 32 + l15) * 64;
    const int ra1 = ra0 + 16 * 64;
    const int rb0 = (wn * 64 + l15) * 64;

    f32x4 acc[4][4] = {};
    const int T = K >> 6;

    u16* const As = sm;           // 4 slots x 8192 u16
    u16* const Bs = sm + 32768;   // 2 slots x 8192 u16

    // prologue: tile0 {A.h0, B, A.h1} then tile1 {A.h0, B}; keep last 4 in flight
    {
        async_load16(Ag + goff0, As + ldso);
        async_load16(Ag + goff1, As + ldso + 4096);
        async_load16(Bg + goff0, Bs + ldso);
        async_load16(Bg + goff1, Bs + ldso + 4096);
        async_load16(Ag + (size_t)128 * K + goff0, As + 8192 + ldso);
        async_load16(Ag + (size_t)128 * K + goff1, As + 8192 + ldso + 4096);
        if (T > 1) {
            async_load16(Ag + 64 + goff0, As + 2 * 8192 + ldso);
            async_load16(Ag + 64 + goff1, As + 2 * 8192 + ldso + 4096);
            async_load16(Bg + 64 + goff0, Bs + 8192 + ldso);
            async_load16(Bg + 64 + goff1, Bs + 8192 + ldso + 4096);
            asm volatile("s_waitcnt vmcnt(4)" ::: "memory");
        } else {
            asm volatile("s_waitcnt vmcnt(0)" ::: "memory");
        }
        asm volatile("s_barrier" ::: "memory");
    }

    for (int t = 0; t < T; ++t) {
        const int par = t & 1;
        const u16* As0 = As + par * 2 * 8192;
        const u16* As1 = As0 + 8192;
        const u16* Bsl = Bs + par * 8192;

        // ---------------- phase A: mf {0,1} from A-half0 --------------------
        bf16x8 bfr[4][2], afr[2][2];
        #pragma unroll
        for (int nf = 0; nf < 4; ++nf) {
            bfr[nf][0] = *(const bf16x8*)(Bsl + rb0 + nf * (16 * 64) + ck0);
            bfr[nf][1] = *(const bf16x8*)(Bsl + rb0 + nf * (16 * 64) + ck1);
        }
        afr[0][0] = *(const bf16x8*)(As0 + ra0 + ck0);
        afr[0][1] = *(const bf16x8*)(As0 + ra0 + ck1);
        afr[1][0] = *(const bf16x8*)(As0 + ra1 + ck0);
        afr[1][1] = *(const bf16x8*)(As0 + ra1 + ck1);
        if (t + 1 < T) {   // stage A.h1(t+1): slot freed at end of tile t-1
            const u16* g = Ag + (size_t)128 * K + (size_t)(t + 1) * 64;
            u16* l = As + ((par ^ 1) * 2 + 1) * 8192;
            async_load16(g + goff0, l + ldso);
            async_load16(g + goff1, l + ldso + 4096);
        }
        asm volatile("s_barrier" ::: "memory");
        __builtin_amdgcn_s_setprio(1);
        #pragma unroll
        for (int m = 0; m < 2; ++m)
            #pragma unroll
            for (int nf = 0; nf < 4; ++nf)
                #pragma unroll
                for (int kk = 0; kk < 2; ++kk)
                    acc[m][nf] = __builtin_amdgcn_mfma_f32_16x16x32_bf16(
                        afr[m][kk], bfr[nf][kk], acc[m][nf], 0, 0, 0);
        __builtin_amdgcn_s_setprio(0);
        asm volatile("s_barrier" ::: "memory");

        // ---------------- phase B: mf {2,3} from A-half1 --------------------
        afr[0][0] = *(const bf16x8*)(As1 + ra0 + ck0);
        afr[0][1] = *(const bf16x8*)(As1 + ra0 + ck1);
        afr[1][0] = *(const bf16x8*)(As1 + ra1 + ck0);
        afr[1][1] = *(const bf16x8*)(As1 + ra1 + ck1);
        if (t + 2 < T) {   // stage A.h0(t+2) + B(t+2): slots freed after phase A
            const u16* ga = Ag + (size_t)(t + 2) * 64;
            const u16* gb = Bg + (size_t)(t + 2) * 64;
            u16* la = As + par * 2 * 8192;
            u16* lb = Bs + par * 8192;
            async_load16(ga + goff0, la + ldso);
            async_load16(ga + goff1, la + ldso + 4096);
            async_load16(gb + goff0, lb + ldso);
            async_load16(gb + goff1, lb + ldso + 4096);
        }
        asm volatile("s_barrier" ::: "memory");
        __builtin_amdgcn_s_setprio(1);
        #pragma unroll
        for (int m = 0; m < 2; ++m)
            #pragma unroll
            for (int nf = 0; nf < 4; ++nf)
                #pragma unroll
                for (int kk = 0; kk < 2; ++kk)
                    acc[2 + m][nf] = __builtin_amdgcn_mfma_f32_16x16x32_bf16(
                        afr[m][kk], bfr[nf][kk], acc[2 + m][nf], 0, 0, 0);
        __builtin_amdgcn_s_setprio(0);
        // tile boundary: counted wait — everything through A.h1(t+1) complete,
        // the 4 phase-B prefetch loads stay in flight across the barrier.
        if (t + 1 < T) {
            if (t + 2 < T) asm volatile("s_waitcnt vmcnt(4)" ::: "memory");
            else           asm volatile("s_waitcnt vmcnt(0)" ::: "memory");
            asm volatile("s_barrier" ::: "memory");
        }
    }

    // epilogue
    #pragma unroll
    for (int mf = 0; mf < 4; ++mf) {
        const int row = m0 + (mf >> 1) * 128 + wm * 32 + (mf & 1) * 16 + q4 * 4;
        #pragma unroll
        for (int nf = 0; nf < 4; ++nf) {
            const int col = n0 + wn * 64 + nf * 16 + l15;
            const float bv = bias[col];
            #pragma unroll
            for (int r = 0; r < 4; ++r) {
                float v = acc[mf][nf][r] + bv;
                if (OUT_BF16) ((u16*)C)[(size_t)(row + r) * N + col] = f2bf(v);
                else          ((float*)C)[(size_t)(row + r) * N + col] = v;
            }
        }
    }
}

// ---- flash attention R6 ----------------------------------------------------
// One Q-tile pass (128 q-rows at qt). Triple-buffered K/V, prefetch-2,
// S^T = K·Q^T -> exp2 -> P^T B-frags in registers -> O^T = V^T·P^T.
__device__ __forceinline__ void stage_tiles(
    const u16* __restrict__ qkv, const u16* __restrict__ vt,
    size_t base, int bh, int h, int w, int srow8, int schunk,
    int kt, u16* __restrict__ KsB, u16* __restrict__ VsB)
{
    #pragma unroll
    for (int q = 0; q < 2; ++q) {
        int rloc = w * 16 + q * 8 + srow8;
        int sc = ((schunk ^ (rloc & 7)) * 8);
        async_load16(qkv + (base + (size_t)kt * 64 + rloc) * (size_t)NQKV + DMODEL + h * HDIM + sc,
                     KsB + (w * 16 + q * 8) * 64);
        async_load16(vt + ((size_t)bh * 64 + rloc) * S_LEN + kt * 64 + sc,
                     VsB + (w * 16 + q * 8) * 64);
    }
}

__device__ __forceinline__ void attn_pass(
    int qt, const u16* __restrict__ qkv, const u16* __restrict__ vt,
    __bf16* __restrict__ outb, u16 (*Ks)[64 * 64], u16 (*Vs)[64 * 64],
    int w, int lane, int bh, int h, size_t base)
{
    const int l15 = lane & 15, q4 = lane >> 4;
    const int srow8 = lane >> 3, schunk = lane & 7;

    // Q fragments for both halves ([n=q=l15][k=d=q4*8+j]); scale folds
    // 1/sqrt(64) * log2(e) so P = 2^(K·Q^T) == e^(K·Q^T/8).
    const float QSCALE = 0.125f * 1.44269504f;
    bf16x8 qf[2][2];
    #pragma unroll
    for (int mh = 0; mh < 2; ++mh) {
        int qrow = qt * 128 + mh * 64 + w * 16 + l15;
        #pragma unroll
        for (int kc = 0; kc < 2; ++kc) {
            bf16x8 raw = *(const bf16x8*)(qkv + (base + qrow) * (size_t)NQKV + h * HDIM + kc * 32 + q4 * 8);
            bf16x8 sc;
            #pragma unroll
            for (int j = 0; j < 8; ++j) sc[j] = (__bf16)((float)raw[j] * QSCALE);
            qf[mh][kc] = sc;
        }
    }

    bf16x4 ones4;
    #pragma unroll
    for (int j = 0; j < 4; ++j) ones4[j] = (__bf16)1.0f;

    f32x4 o0[4] = {}, o1[4] = {};   // O^T: [d-tile mt][q=l15], rows d=q4*4+r
    f32x4 la0 = {}, la1 = {};       // l[q=l15]

    const int ktlast = 2 * qt + 1;  // tail tile (half-0 fully masked)

    __syncthreads();                // protect LDS reuse across passes
    stage_tiles(qkv, vt, base, bh, h, w, srow8, schunk, 0, Ks[0], Vs[0]);
    if (ktlast >= 1)
        stage_tiles(qkv, vt, base, bh, h, w, srow8, schunk, 1, Ks[1], Vs[1]);

    for (int kt = 0; kt <= 2 * qt; ++kt) {
        const int buf = kt % 3;
        __syncthreads();            // kt,kt+1 staged; reads of buf (kt+2)%3 done
        int pf = kt + 2;
        if (pf <= ktlast)
            stage_tiles(qkv, vt, base, bh, h, w, srow8, schunk, pf, Ks[pf % 3], Vs[pf % 3]);

        // S^T = K·Q^T; kf shared across halves
        f32x4 st0[4] = {}, st1[4] = {};
        #pragma unroll
        for (int nt = 0; nt < 4; ++nt) {
            int n = nt * 16 + l15;      // key row in Ks
            #pragma unroll
            for (int kc = 0; kc < 2; ++kc) {
                int ch = (((kc * 4 + q4) ^ (n & 7)) * 8);
                bf16x8 kf = *(const bf16x8*)(&Ks[buf][n * 64 + ch]);
                st0[nt] = __builtin_amdgcn_mfma_f32_16x16x32_bf16(kf, qf[0][kc], st0[nt], 0, 0, 0);
                st1[nt] = __builtin_amdgcn_mfma_f32_16x16x32_bf16(kf, qf[1][kc], st1[nt], 0, 0, 0);
            }
        }

        if (kt == 2 * qt) {             // diagonal for half 0 (uniform branch)
            #pragma unroll
            for (int nt = 0; nt < 4; ++nt)
                #pragma unroll
                for (int r = 0; r < 4; ++r) {
                    int keyl = nt * 16 + q4 * 4 + r;
                    if (keyl > w * 16 + l15) st0[nt][r] = -1e30f;
                }
        }

        // P^T = 2^(S^T) packed to bf16x4 B-frags (k = q4*4+j), in registers
        bf16x4 pb0[4], pb1[4];
        #pragma unroll
        for (int nt = 0; nt < 4; ++nt)
            #pragma unroll
            for (int r = 0; r < 4; ++r) {
                pb0[nt][r] = (__bf16)__builtin_amdgcn_exp2f(st0[nt][r]);
                pb1[nt][r] = (__bf16)__builtin_amdgcn_exp2f(st1[nt][r]);
            }

        // O^T += V^T · P^T  (vf shared across halves); l += ones · P^T
        #pragma unroll
        for (int nt = 0; nt < 4; ++nt) {
            #pragma unroll
            for (int mt = 0; mt < 4; ++mt) {
                int row = mt * 16 + l15;                       // d row in Vs
                int ch = (nt * 2 + (q4 >> 1)) ^ (row & 7);
                bf16x4 vf = *(const bf16x4*)(&Vs[buf][row * 64 + ch * 8 + (q4 & 1) * 4]);
                o0[mt] = mfma16(vf, pb0[nt], o0[mt]);
                o1[mt] = mfma16(vf, pb1[nt], o1[mt]);
            }
            la0 = mfma16(ones4, pb0[nt], la0);
            la1 = mfma16(ones4, pb1[nt], la1);
        }
    }

    // ---- tail tile ktlast: half 0 fully masked; half 1 only ----------------
    {
        const int buf = ktlast % 3;
        __syncthreads();

        f32x4 st1[4] = {};
        #pragma unroll
        for (int nt = 0; nt < 4; ++nt) {
            int n = nt * 16 + l15;
            #pragma unroll
            for (int kc = 0; kc < 2; ++kc) {
                int ch = (((kc * 4 + q4) ^ (n & 7)) * 8);
                bf16x8 kf = *(const bf16x8*)(&Ks[buf][n * 64 + ch]);
                st1[nt] = __builtin_amdgcn_mfma_f32_16x16x32_bf16(kf, qf[1][kc], st1[nt], 0, 0, 0);
            }
        }
        bf16x4 pb1[4];
        #pragma unroll
        for (int nt = 0; nt < 4; ++nt)
            #pragma unroll
            for (int r = 0; r < 4; ++r) {
                int keyl = nt * 16 + q4 * 4 + r;
                float s = (keyl > w * 16 + l15) ? -1e30f : st1[nt][r];
                pb1[nt][r] = (__bf16)__builtin_amdgcn_exp2f(s);
            }
        #pragma unroll
        for (int nt = 0; nt < 4; ++nt) {
            #pragma unroll
            for (int mt = 0; mt < 4; ++mt) {
                int row = mt * 16 + l15;
                int ch = (nt * 2 + (q4 >> 1)) ^ (row & 7);
                bf16x4 vf = *(const bf16x4*)(&Vs[buf][row * 64 + ch * 8 + (q4 & 1) * 4]);
                o1[mt] = mfma16(vf, pb1[nt], o1[mt]);
            }
            la1 = mfma16(ones4, pb1[nt], la1);
        }
    }

    // epilogue: lane holds O^T[d = mt*16+q4*4+r][q=l15]; packed 8B stores
    float inv0 = 1.0f / la0[0], inv1 = 1.0f / la1[0];
    int row0 = qt * 128 + w * 16 + l15;
    int row1 = row0 + 64;
    #pragma unroll
    for (int mt = 0; mt < 4; ++mt) {
        union { __bf16 b[4]; ushort4 v; } p0, p1;
        #pragma unroll
        for (int r = 0; r < 4; ++r) {
            p0.b[r] = (__bf16)(o0[mt][r] * inv0);
            p1.b[r] = (__bf16)(o1[mt][r] * inv1);
        }
        int col = h * HDIM + mt * 16 + q4 * 4;
        *(ushort4*)(&outb[(base + row0) * (size_t)DMODEL + col]) = p0.v;
        *(ushort4*)(&outb[(base + row1) * (size_t)DMODEL + col]) = p1.v;
    }
}

// block = (bx, bh): processes Q-tiles qt = NT-1-bx and qt = bx (34 K-iters
// total for every block -> perfect load balance). gridDim.x = NT/2 = 8.
__global__ __launch_bounds__(256, 3) void attn_kernel(
    const u16* __restrict__ qkv, const u16* __restrict__ vt, u16* __restrict__ out)
{
    __shared__ __attribute__((aligned(16))) u16 Ks[3][64 * 64];
    __shared__ __attribute__((aligned(16))) u16 Vs[3][64 * 64];

    const int tid = threadIdx.x;
    const int w = tid >> 6, lane = tid & 63;
    const int bh = blockIdx.y;
    const int b = bh >> 4, h = bh & 15;
    const size_t base = (size_t)b * S_LEN;
    const int NT = (int)gridDim.x * 2;           // 16

    attn_pass(NT - 1 - (int)blockIdx.x, qkv, vt, (__bf16*)out, Ks, Vs, w, lane, bh, h, base);
    attn_pass((int)blockIdx.x,          qkv, vt, (__bf16*)out, Ks, Vs, w, lane, bh, h, base);
}

extern "C" void kernel_launch(void* const* d_in, const int* in_sizes, int n_in,
                              void* d_out, int out_size, void* d_ws, size_t ws_size,
                              hipStream_t stream) {
    const float* x      = (const float*)d_in[0];
    // d_in[1] = mask (causal tril) — implemented structurally, not read
    const float* w_attn = (const float*)d_in[2];
    const float* b_attn = (const float*)d_in[3];
    const float* w_proj = (const float*)d_in[4];
    const float* b_proj = (const float*)d_in[5];

    u16* xb   = (u16*)d_ws;                                   // 8192x1024 (dead after QKV GEMM)
    u16* wat  = xb  + (size_t)MTOT * DMODEL;                  // 3072x1024
    u16* wpt  = wat + (size_t)NQKV * DMODEL;                  // 1024x1024
    u16* qkv  = wpt + (size_t)DMODEL * DMODEL;                // 8192x3072
    u16* attn = qkv + (size_t)MTOT * NQKV;                    // 8192x1024
    u16* vt   = xb;                                           // Vt[64 bh][64 d][2048 s] aliases xb

    convert_x_kernel<<<(MTOT * DMODEL / 4 + 255) / 256, 256, 0, stream>>>(
        (const float4*)x, (ushort4*)xb, MTOT * DMODEL / 4);
    transpose_bf16_kernel<<<dim3(NQKV / 64, DMODEL / 64), 256, 0, stream>>>(w_attn, wat, DMODEL, NQKV);
    transpose_bf16_kernel<<<dim3(DMODEL / 64, DMODEL / 64), 256, 0, stream>>>(w_proj, wpt, DMODEL, DMODEL);

    gemm256<true><<<dim3((MTOT / 256) * (NQKV / 128)), 512, 0, stream>>>(
        xb, wat, b_attn, (void*)qkv, MTOT, NQKV, DMODEL);

    transpose_v_kernel<<<dim3(S_LEN / 64, 4 * NHEAD), 256, 0, stream>>>(qkv, vt);

    attn_kernel<<<dim3(S_LEN / 256, 4 * NHEAD), 256, 0, stream>>>(qkv, vt, attn);

    gemm256<false><<<dim3((MTOT / 256) * (DMODEL / 128)), 512, 0, stream>>>(
        attn, wpt, b_proj, d_out, MTOT, DMODEL, DMODEL);
}

// Round 2
// 267.713 us; speedup vs baseline: 1.0647x; 1.0647x over previous
//
#include <hip/hip_runtime.h>
#include <hip/hip_bf16.h>
#include <stdint.h>

// ---------------------------------------------------------------------------
// CausalSelfAttention: x(4,2048,1024) fp32 -> out fp32
// qkv = x@w_attn+b_attn; flash-attn causal (H=16,hd=64); out = attn@w_proj+b_proj
// R8: gemm256 block mapping fixed. R7's mapping made each XCD sweep the FULL
//   16MB A per nb column -> FETCH 58->200MB, L2-miss latency stalled the
//   counted-vmcnt pipeline (MfmaUtil 26%). Now: xcd = bid&7 (round-robin),
//   each XCD owns a FIXED 4-mb-row A panel (2MB, L2-resident all kernel) and
//   sweeps nb; concurrent set = 2MB A + 2MB B = 4MB = XCD L2. Pipeline,
//   swizzle (T2), counted vmcnt (T3+T4), setprio (T5) unchanged from R7.
// attn (R6): paired Q-tiles, triple-buffered K/V ring, exp2 softmax (unchanged).
// Workspace: xb 16MB (aliased by Vt after QKV GEMM) | wat 6MB | wpt 2MB |
//            qkv 48MB | attn 16MB  = 88 MB
// ---------------------------------------------------------------------------

typedef uint16_t u16;
typedef __bf16 bf16x8 __attribute__((ext_vector_type(8)));
typedef __bf16 bf16x4 __attribute__((ext_vector_type(4)));
typedef short s16x4 __attribute__((ext_vector_type(4)));
typedef float f32x4 __attribute__((ext_vector_type(4)));

#define S_LEN 2048
#define DMODEL 1024
#define NHEAD 16
#define HDIM 64
#define MTOT 8192   // B*S
#define NQKV 3072

__device__ __forceinline__ u16 f2bf(float f) {
    union { float f; uint32_t u; } v; v.f = f;
    uint32_t u = v.u;
    return (u16)((u + 0x7fffu + ((u >> 16) & 1u)) >> 16);  // RNE
}

__device__ __forceinline__ s16x4 bits4(bf16x4 v) {
    union { bf16x4 b; s16x4 s; } u; u.b = v; return u.s;
}

// D = A*B + C, 16x16x16 bf16 (A,B: 4 bf16/lane, k = q4*4+j)
__device__ __forceinline__ f32x4 mfma16(bf16x4 a, bf16x4 b, f32x4 c) {
    return __builtin_amdgcn_mfma_f32_16x16x16bf16_1k(bits4(a), bits4(b), c, 0, 0, 0);
}

__device__ __forceinline__ void async_load16(const void* g, void* l) {
    __builtin_amdgcn_global_load_lds(
        (__attribute__((address_space(1))) void*)g,
        (__attribute__((address_space(3))) void*)l,
        16, 0, 0);
}

// ---- prep: fp32 -> bf16 (vectorized) --------------------------------------
__global__ void convert_x_kernel(const float4* __restrict__ in, ushort4* __restrict__ out, int n4) {
    int i = blockIdx.x * 256 + threadIdx.x;
    if (i < n4) {
        float4 f = in[i];
        ushort4 o;
        o.x = f2bf(f.x); o.y = f2bf(f.y); o.z = f2bf(f.z); o.w = f2bf(f.w);
        out[i] = o;
    }
}

// ---- prep: transpose + convert: in (R x C) fp32 -> out (C x R) bf16 --------
__global__ void transpose_bf16_kernel(const float* __restrict__ in, u16* __restrict__ out, int R, int C) {
    __shared__ float tile[64][65];
    int r0 = blockIdx.y * 64, c0 = blockIdx.x * 64;
    #pragma unroll
    for (int i = 0; i < 16; ++i) {
        int idx = threadIdx.x + i * 256;
        int r = idx >> 6, c = idx & 63;
        tile[r][c] = in[(size_t)(r0 + r) * C + c0 + c];
    }
    __syncthreads();
    #pragma unroll
    for (int i = 0; i < 16; ++i) {
        int idx = threadIdx.x + i * 256;
        int c = idx >> 6, r = idx & 63;
        out[(size_t)(c0 + c) * R + r0 + r] = f2bf(tile[r][c]);
    }
}

// ---- V transpose: qkv V-section (token-major) -> Vt[bh][d][s] --------------
__global__ void transpose_v_kernel(const u16* __restrict__ qkv, u16* __restrict__ vt) {
    __shared__ u16 tile[64 * 66];
    const int tid = threadIdx.x;
    const int stile = blockIdx.x, bh = blockIdx.y;
    const int b = bh >> 4, h = bh & 15;
    const u16* src = qkv + ((size_t)b * S_LEN + stile * 64) * NQKV + 2 * DMODEL + h * HDIM;
    #pragma unroll
    for (int it = 0; it < 2; ++it) {
        int item = it * 256 + tid;
        int s = item >> 3, d0 = (item & 7) * 8;
        bf16x8 v = *(const bf16x8*)(src + (size_t)s * NQKV + d0);
        const u16* vu = (const u16*)&v;
        #pragma unroll
        for (int j = 0; j < 8; ++j) tile[(d0 + j) * 66 + s] = vu[j];
    }
    __syncthreads();
    #pragma unroll
    for (int it = 0; it < 2; ++it) {
        int item = it * 256 + tid;
        int d = item >> 3, s0 = (item & 7) * 8;
        union { u16 u[8]; uint4 v; } pk;
        #pragma unroll
        for (int j = 0; j < 8; ++j) pk.u[j] = tile[d * 66 + s0 + j];
        *(uint4*)(vt + ((size_t)bh * 64 + d) * S_LEN + stile * 64 + s0) = pk.v;
    }
}

// ---- GEMM256: C[M,N] = A[M,K] @ Bt[N,K]^T + bias ---------------------------
// BM=256, BN=128, BK=64; 512 threads = 8 waves (wm=wave&3 along M, wn=wave>>2
// along N), per-wave 64x64 output (mf 0..3, nf 0..3, 16x16x32 MFMA).
// LDS ring (96 KiB): A = 4 half-slots [parity][half] of 128x64 bf16 (16KB),
// B = 2 slots of 128x64. Element (r,k): chunk (k>>3) stored at slot
// chunk^(r&7)  -> ds_read_b128 conflict-free; staging writes LINEAR LDS
// (global_load_lds) from inverse-swizzled global source (both-sides rule).
// Per K-tile: phase A computes mf{0,1} from A-half0 (B-frags read once, held
// in regs), phase B computes mf{2,3} from A-half1. Each half-slot is read in
// exactly one phase -> freed mid-tile for the prefetch ring:
//   phase A stages A.h1(t+1); phase B stages A.h0(t+2)+B(t+2);
//   boundary wait = s_waitcnt vmcnt(4) (the 4 phase-B loads stay in flight).
// Block mapping (R8): xcd = bid&7; each XCD keeps a fixed 4-row A panel
// (2MB, L2-resident) and sweeps nb; concurrent set 4MB = XCD L2.
// Requires M%256==0, N%128==0, K%64==0, grid = (M/256)*(N/128), M/256 % 8 == 0.
template<bool OUT_BF16>
__global__ __launch_bounds__(512, 2) void gemm256(
    const u16* __restrict__ A, const u16* __restrict__ Bt,
    const float* __restrict__ bias, void* __restrict__ C,
    int M, int N, int K)
{
    __shared__ __attribute__((aligned(16))) u16 sm[49152];   // 96 KiB
    const int tid = threadIdx.x;
    const int wave = tid >> 6, lane = tid & 63;
    const int l15 = lane & 15, q4 = lane >> 4;
    const int wm = wave & 3, wn = wave >> 2;

    // XCD-resident A-panel mapping
    const int bid = (int)blockIdx.x;
    const int xcd = bid & 7;
    const int l   = bid >> 3;
    const int MB  = M >> 8;                // 32
    const int PM  = MB >> 3;               // 4 rows per XCD panel
    const int nb  = l / PM;
    const int mb  = xcd * PM + (l - nb * PM);
    const int m0 = mb << 8, n0 = nb << 7;

    const u16* Ag = A + (size_t)m0 * K;
    const u16* Bg = Bt + (size_t)n0 * K;

    // staging: per thread 2x16B per half-tile; linear LDS dest, swizzled src
    const int srow = tid >> 3;
    const size_t goff0 = (size_t)srow * K + (size_t)(((tid & 7) ^ (srow & 7)) * 8);
    const size_t goff1 = goff0 + (size_t)64 * K;
    const int ldso = tid * 8;

    // ds_read offsets (u16 units); r&7 == l15&7 for all frag rows
    const int ck0 = (q4 ^ (l15 & 7)) * 8;
    const int ck1 = ((4 + q4) ^ (l15 & 7)) * 8;
    const int ra0 = (wm * 32 + l15) * 64;
    const int ra1 = ra0 + 16 * 64;
    const int rb0 = (wn * 64 + l15) * 64;

    f32x4 acc[4][4] = {};
    const int T = K >> 6;

    u16* const As = sm;           // 4 slots x 8192 u16
    u16* const Bs = sm + 32768;   // 2 slots x 8192 u16

    // prologue: tile0 {A.h0, B, A.h1} then tile1 {A.h0, B}; keep last 4 in flight
    {
        async_load16(Ag + goff0, As + ldso);
        async_load16(Ag + goff1, As + ldso + 4096);
        async_load16(Bg + goff0, Bs + ldso);
        async_load16(Bg + goff1, Bs + ldso + 4096);
        async_load16(Ag + (size_t)128 * K + goff0, As + 8192 + ldso);
        async_load16(Ag + (size_t)128 * K + goff1, As + 8192 + ldso + 4096);
        if (T > 1) {
            async_load16(Ag + 64 + goff0, As + 2 * 8192 + ldso);
            async_load16(Ag + 64 + goff1, As + 2 * 8192 + ldso + 4096);
            async_load16(Bg + 64 + goff0, Bs + 8192 + ldso);
            async_load16(Bg + 64 + goff1, Bs + 8192 + ldso + 4096);
            asm volatile("s_waitcnt vmcnt(4)" ::: "memory");
        } else {
            asm volatile("s_waitcnt vmcnt(0)" ::: "memory");
        }
        asm volatile("s_barrier" ::: "memory");
    }

    for (int t = 0; t < T; ++t) {
        const int par = t & 1;
        const u16* As0 = As + par * 2 * 8192;
        const u16* As1 = As0 + 8192;
        const u16* Bsl = Bs + par * 8192;

        // ---------------- phase A: mf {0,1} from A-half0 --------------------
        bf16x8 bfr[4][2], afr[2][2];
        #pragma unroll
        for (int nf = 0; nf < 4; ++nf) {
            bfr[nf][0] = *(const bf16x8*)(Bsl + rb0 + nf * (16 * 64) + ck0);
            bfr[nf][1] = *(const bf16x8*)(Bsl + rb0 + nf * (16 * 64) + ck1);
        }
        afr[0][0] = *(const bf16x8*)(As0 + ra0 + ck0);
        afr[0][1] = *(const bf16x8*)(As0 + ra0 + ck1);
        afr[1][0] = *(const bf16x8*)(As0 + ra1 + ck0);
        afr[1][1] = *(const bf16x8*)(As0 + ra1 + ck1);
        if (t + 1 < T) {   // stage A.h1(t+1): slot freed at end of tile t-1
            const u16* g = Ag + (size_t)128 * K + (size_t)(t + 1) * 64;
            u16* l2 = As + ((par ^ 1) * 2 + 1) * 8192;
            async_load16(g + goff0, l2 + ldso);
            async_load16(g + goff1, l2 + ldso + 4096);
        }
        asm volatile("s_barrier" ::: "memory");
        __builtin_amdgcn_s_setprio(1);
        #pragma unroll
        for (int m = 0; m < 2; ++m)
            #pragma unroll
            for (int nf = 0; nf < 4; ++nf)
                #pragma unroll
                for (int kk = 0; kk < 2; ++kk)
                    acc[m][nf] = __builtin_amdgcn_mfma_f32_16x16x32_bf16(
                        afr[m][kk], bfr[nf][kk], acc[m][nf], 0, 0, 0);
        __builtin_amdgcn_s_setprio(0);
        asm volatile("s_barrier" ::: "memory");

        // ---------------- phase B: mf {2,3} from A-half1 --------------------
        afr[0][0] = *(const bf16x8*)(As1 + ra0 + ck0);
        afr[0][1] = *(const bf16x8*)(As1 + ra0 + ck1);
        afr[1][0] = *(const bf16x8*)(As1 + ra1 + ck0);
        afr[1][1] = *(const bf16x8*)(As1 + ra1 + ck1);
        if (t + 2 < T) {   // stage A.h0(t+2) + B(t+2): slots freed after phase A
            const u16* ga = Ag + (size_t)(t + 2) * 64;
            const u16* gb = Bg + (size_t)(t + 2) * 64;
            u16* la = As + par * 2 * 8192;
            u16* lb = Bs + par * 8192;
            async_load16(ga + goff0, la + ldso);
            async_load16(ga + goff1, la + ldso + 4096);
            async_load16(gb + goff0, lb + ldso);
            async_load16(gb + goff1, lb + ldso + 4096);
        }
        asm volatile("s_barrier" ::: "memory");
        __builtin_amdgcn_s_setprio(1);
        #pragma unroll
        for (int m = 0; m < 2; ++m)
            #pragma unroll
            for (int nf = 0; nf < 4; ++nf)
                #pragma unroll
                for (int kk = 0; kk < 2; ++kk)
                    acc[2 + m][nf] = __builtin_amdgcn_mfma_f32_16x16x32_bf16(
                        afr[m][kk], bfr[nf][kk], acc[2 + m][nf], 0, 0, 0);
        __builtin_amdgcn_s_setprio(0);
        // tile boundary: counted wait — everything through A.h1(t+1) complete,
        // the 4 phase-B prefetch loads stay in flight across the barrier.
        if (t + 1 < T) {
            if (t + 2 < T) asm volatile("s_waitcnt vmcnt(4)" ::: "memory");
            else           asm volatile("s_waitcnt vmcnt(0)" ::: "memory");
            asm volatile("s_barrier" ::: "memory");
        }
    }

    // epilogue
    #pragma unroll
    for (int mf = 0; mf < 4; ++mf) {
        const int row = m0 + (mf >> 1) * 128 + wm * 32 + (mf & 1) * 16 + q4 * 4;
        #pragma unroll
        for (int nf = 0; nf < 4; ++nf) {
            const int col = n0 + wn * 64 + nf * 16 + l15;
            const float bv = bias[col];
            #pragma unroll
            for (int r = 0; r < 4; ++r) {
                float v = acc[mf][nf][r] + bv;
                if (OUT_BF16) ((u16*)C)[(size_t)(row + r) * N + col] = f2bf(v);
                else          ((float*)C)[(size_t)(row + r) * N + col] = v;
            }
        }
    }
}

// ---- flash attention R6 ----------------------------------------------------
// One Q-tile pass (128 q-rows at qt). Triple-buffered K/V, prefetch-2,
// S^T = K·Q^T -> exp2 -> P^T B-frags in registers -> O^T = V^T·P^T.
__device__ __forceinline__ void stage_tiles(
    const u16* __restrict__ qkv, const u16* __restrict__ vt,
    size_t base, int bh, int h, int w, int srow8, int schunk,
    int kt, u16* __restrict__ KsB, u16* __restrict__ VsB)
{
    #pragma unroll
    for (int q = 0; q < 2; ++q) {
        int rloc = w * 16 + q * 8 + srow8;
        int sc = ((schunk ^ (rloc & 7)) * 8);
        async_load16(qkv + (base + (size_t)kt * 64 + rloc) * (size_t)NQKV + DMODEL + h * HDIM + sc,
                     KsB + (w * 16 + q * 8) * 64);
        async_load16(vt + ((size_t)bh * 64 + rloc) * S_LEN + kt * 64 + sc,
                     VsB + (w * 16 + q * 8) * 64);
    }
}

__device__ __forceinline__ void attn_pass(
    int qt, const u16* __restrict__ qkv, const u16* __restrict__ vt,
    __bf16* __restrict__ outb, u16 (*Ks)[64 * 64], u16 (*Vs)[64 * 64],
    int w, int lane, int bh, int h, size_t base)
{
    const int l15 = lane & 15, q4 = lane >> 4;
    const int srow8 = lane >> 3, schunk = lane & 7;

    // Q fragments for both halves ([n=q=l15][k=d=q4*8+j]); scale folds
    // 1/sqrt(64) * log2(e) so P = 2^(K·Q^T) == e^(K·Q^T/8).
    const float QSCALE = 0.125f * 1.44269504f;
    bf16x8 qf[2][2];
    #pragma unroll
    for (int mh = 0; mh < 2; ++mh) {
        int qrow = qt * 128 + mh * 64 + w * 16 + l15;
        #pragma unroll
        for (int kc = 0; kc < 2; ++kc) {
            bf16x8 raw = *(const bf16x8*)(qkv + (base + qrow) * (size_t)NQKV + h * HDIM + kc * 32 + q4 * 8);
            bf16x8 sc;
            #pragma unroll
            for (int j = 0; j < 8; ++j) sc[j] = (__bf16)((float)raw[j] * QSCALE);
            qf[mh][kc] = sc;
        }
    }

    bf16x4 ones4;
    #pragma unroll
    for (int j = 0; j < 4; ++j) ones4[j] = (__bf16)1.0f;

    f32x4 o0[4] = {}, o1[4] = {};   // O^T: [d-tile mt][q=l15], rows d=q4*4+r
    f32x4 la0 = {}, la1 = {};       // l[q=l15]

    const int ktlast = 2 * qt + 1;  // tail tile (half-0 fully masked)

    __syncthreads();                // protect LDS reuse across passes
    stage_tiles(qkv, vt, base, bh, h, w, srow8, schunk, 0, Ks[0], Vs[0]);
    if (ktlast >= 1)
        stage_tiles(qkv, vt, base, bh, h, w, srow8, schunk, 1, Ks[1], Vs[1]);

    for (int kt = 0; kt <= 2 * qt; ++kt) {
        const int buf = kt % 3;
        __syncthreads();            // kt,kt+1 staged; reads of buf (kt+2)%3 done
        int pf = kt + 2;
        if (pf <= ktlast)
            stage_tiles(qkv, vt, base, bh, h, w, srow8, schunk, pf, Ks[pf % 3], Vs[pf % 3]);

        // S^T = K·Q^T; kf shared across halves
        f32x4 st0[4] = {}, st1[4] = {};
        #pragma unroll
        for (int nt = 0; nt < 4; ++nt) {
            int n = nt * 16 + l15;      // key row in Ks
            #pragma unroll
            for (int kc = 0; kc < 2; ++kc) {
                int ch = (((kc * 4 + q4) ^ (n & 7)) * 8);
                bf16x8 kf = *(const bf16x8*)(&Ks[buf][n * 64 + ch]);
                st0[nt] = __builtin_amdgcn_mfma_f32_16x16x32_bf16(kf, qf[0][kc], st0[nt], 0, 0, 0);
                st1[nt] = __builtin_amdgcn_mfma_f32_16x16x32_bf16(kf, qf[1][kc], st1[nt], 0, 0, 0);
            }
        }

        if (kt == 2 * qt) {             // diagonal for half 0 (uniform branch)
            #pragma unroll
            for (int nt = 0; nt < 4; ++nt)
                #pragma unroll
                for (int r = 0; r < 4; ++r) {
                    int keyl = nt * 16 + q4 * 4 + r;
                    if (keyl > w * 16 + l15) st0[nt][r] = -1e30f;
                }
        }

        // P^T = 2^(S^T) packed to bf16x4 B-frags (k = q4*4+j), in registers
        bf16x4 pb0[4], pb1[4];
        #pragma unroll
        for (int nt = 0; nt < 4; ++nt)
            #pragma unroll
            for (int r = 0; r < 4; ++r) {
                pb0[nt][r] = (__bf16)__builtin_amdgcn_exp2f(st0[nt][r]);
                pb1[nt][r] = (__bf16)__builtin_amdgcn_exp2f(st1[nt][r]);
            }

        // O^T += V^T · P^T  (vf shared across halves); l += ones · P^T
        #pragma unroll
        for (int nt = 0; nt < 4; ++nt) {
            #pragma unroll
            for (int mt = 0; mt < 4; ++mt) {
                int row = mt * 16 + l15;                       // d row in Vs
                int ch = (nt * 2 + (q4 >> 1)) ^ (row & 7);
                bf16x4 vf = *(const bf16x4*)(&Vs[buf][row * 64 + ch * 8 + (q4 & 1) * 4]);
                o0[mt] = mfma16(vf, pb0[nt], o0[mt]);
                o1[mt] = mfma16(vf, pb1[nt], o1[mt]);
            }
            la0 = mfma16(ones4, pb0[nt], la0);
            la1 = mfma16(ones4, pb1[nt], la1);
        }
    }

    // ---- tail tile ktlast: half 0 fully masked; half 1 only ----------------
    {
        const int buf = ktlast % 3;
        __syncthreads();

        f32x4 st1[4] = {};
        #pragma unroll
        for (int nt = 0; nt < 4; ++nt) {
            int n = nt * 16 + l15;
            #pragma unroll
            for (int kc = 0; kc < 2; ++kc) {
                int ch = (((kc * 4 + q4) ^ (n & 7)) * 8);
                bf16x8 kf = *(const bf16x8*)(&Ks[buf][n * 64 + ch]);
                st1[nt] = __builtin_amdgcn_mfma_f32_16x16x32_bf16(kf, qf[1][kc], st1[nt], 0, 0, 0);
            }
        }
        bf16x4 pb1[4];
        #pragma unroll
        for (int nt = 0; nt < 4; ++nt)
            #pragma unroll
            for (int r = 0; r < 4; ++r) {
                int keyl = nt * 16 + q4 * 4 + r;
                float s = (keyl > w * 16 + l15) ? -1e30f : st1[nt][r];
                pb1[nt][r] = (__bf16)__builtin_amdgcn_exp2f(s);
            }
        #pragma unroll
        for (int nt = 0; nt < 4; ++nt) {
            #pragma unroll
            for (int mt = 0; mt < 4; ++mt) {
                int row = mt * 16 + l15;
                int ch = (nt * 2 + (q4 >> 1)) ^ (row & 7);
                bf16x4 vf = *(const bf16x4*)(&Vs[buf][row * 64 + ch * 8 + (q4 & 1) * 4]);
                o1[mt] = mfma16(vf, pb1[nt], o1[mt]);
            }
            la1 = mfma16(ones4, pb1[nt], la1);
        }
    }

    // epilogue: lane holds O^T[d = mt*16+q4*4+r][q=l15]; packed 8B stores
    float inv0 = 1.0f / la0[0], inv1 = 1.0f / la1[0];
    int row0 = qt * 128 + w * 16 + l15;
    int row1 = row0 + 64;
    #pragma unroll
    for (int mt = 0; mt < 4; ++mt) {
        union { __bf16 b[4]; ushort4 v; } p0, p1;
        #pragma unroll
        for (int r = 0; r < 4; ++r) {
            p0.b[r] = (__bf16)(o0[mt][r] * inv0);
            p1.b[r] = (__bf16)(o1[mt][r] * inv1);
        }
        int col = h * HDIM + mt * 16 + q4 * 4;
        *(ushort4*)(&outb[(base + row0) * (size_t)DMODEL + col]) = p0.v;
        *(ushort4*)(&outb[(base + row1) * (size_t)DMODEL + col]) = p1.v;
    }
}

// block = (bx, bh): processes Q-tiles qt = NT-1-bx and qt = bx (34 K-iters
// total for every block -> perfect load balance). gridDim.x = NT/2 = 8.
__global__ __launch_bounds__(256, 3) void attn_kernel(
    const u16* __restrict__ qkv, const u16* __restrict__ vt, u16* __restrict__ out)
{
    __shared__ __attribute__((aligned(16))) u16 Ks[3][64 * 64];
    __shared__ __attribute__((aligned(16))) u16 Vs[3][64 * 64];

    const int tid = threadIdx.x;
    const int w = tid >> 6, lane = tid & 63;
    const int bh = blockIdx.y;
    const int b = bh >> 4, h = bh & 15;
    const size_t base = (size_t)b * S_LEN;
    const int NT = (int)gridDim.x * 2;           // 16

    attn_pass(NT - 1 - (int)blockIdx.x, qkv, vt, (__bf16*)out, Ks, Vs, w, lane, bh, h, base);
    attn_pass((int)blockIdx.x,          qkv, vt, (__bf16*)out, Ks, Vs, w, lane, bh, h, base);
}

extern "C" void kernel_launch(void* const* d_in, const int* in_sizes, int n_in,
                              void* d_out, int out_size, void* d_ws, size_t ws_size,
                              hipStream_t stream) {
    const float* x      = (const float*)d_in[0];
    // d_in[1] = mask (causal tril) — implemented structurally, not read
    const float* w_attn = (const float*)d_in[2];
    const float* b_attn = (const float*)d_in[3];
    const float* w_proj = (const float*)d_in[4];
    const float* b_proj = (const float*)d_in[5];

    u16* xb   = (u16*)d_ws;                                   // 8192x1024 (dead after QKV GEMM)
    u16* wat  = xb  + (size_t)MTOT * DMODEL;                  // 3072x1024
    u16* wpt  = wat + (size_t)NQKV * DMODEL;                  // 1024x1024
    u16* qkv  = wpt + (size_t)DMODEL * DMODEL;                // 8192x3072
    u16* attn = qkv + (size_t)MTOT * NQKV;                    // 8192x1024
    u16* vt   = xb;                                           // Vt[64 bh][64 d][2048 s] aliases xb

    convert_x_kernel<<<(MTOT * DMODEL / 4 + 255) / 256, 256, 0, stream>>>(
        (const float4*)x, (ushort4*)xb, MTOT * DMODEL / 4);
    transpose_bf16_kernel<<<dim3(NQKV / 64, DMODEL / 64), 256, 0, stream>>>(w_attn, wat, DMODEL, NQKV);
    transpose_bf16_kernel<<<dim3(DMODEL / 64, DMODEL / 64), 256, 0, stream>>>(w_proj, wpt, DMODEL, DMODEL);

    gemm256<true><<<dim3((MTOT / 256) * (NQKV / 128)), 512, 0, stream>>>(
        xb, wat, b_attn, (void*)qkv, MTOT, NQKV, DMODEL);

    transpose_v_kernel<<<dim3(S_LEN / 64, 4 * NHEAD), 256, 0, stream>>>(qkv, vt);

    attn_kernel<<<dim3(S_LEN / 256, 4 * NHEAD), 256, 0, stream>>>(qkv, vt, attn);

    gemm256<false><<<dim3((MTOT / 256) * (DMODEL / 128)), 512, 0, stream>>>(
        attn, wpt, b_proj, d_out, MTOT, DMODEL, DMODEL);
}